// Round 5
// baseline (189.217 us; speedup 1.0000x reference)
//
#include <hip/hip_runtime.h>

// SSIM (win=11, sigma=1.5, range=255), N=16 C=3 512x512 fp32 -> [16,502,502].
// R5: software-pipelined channel loop (R4 was latency-bound: all pipes <33%,
// serial stage->barrier->compute chain per channel).
//  - channel ch+1's global loads prefetched into float4 regs DURING channel
//    ch's MFMA section (issued after barrier B so the barrier's vmcnt(0)
//    drain doesn't flush them)
//  - write phase = regs -> cvt f16 -> ds_write only (no global latency)
//  - edge-column blocks: per-chunk clamp (16/20 chunks stay vector loads)
//  LDS 29.7 kB; __launch_bounds__(256,4); VGPR target <=128.
//
// MFMA scheme (mfma_f32_16x16x32_f16), B[k][n] = W[k-n] banded, both passes:
//  H: A[m=row][k=stagedcol] -> D[m=row][n=outcol]; C-layout lane holds
//     4 consecutive rows at one outcol -> ds_write_b64 transposed H_T.
//  V: A[m=outcol][k=row] from H_T (k contiguous -> ds_read_b128),
//     D[m=outcol][n=outrow]. Wave owns outcol chunk for both -> no barrier.
//  x^2/y^2/xy A-fragments derived in registers (v_pk_mul_f16 of x/y frags).
//  s_ht is a wave-private ping-pong (per-wave DS ordering; validated R3/R4).

namespace {

constexpr int NN = 16, CC = 3, HH = 512, WW = 512;
constexpr int OH = HH - 10, OW = WW - 10;          // 502 x 502
constexpr int TW = 64, TH = 32;                    // output tile
constexpr int SROWS = 48, SREAL = 42;              // staged rows (42 real)
constexpr int SCOLS = 80, SPITCH = 88;             // staged cols, f16 pitch
constexpr int SCHUNKS = SCOLS / 4;                 // 20 float4 chunks/row
constexpr int SITEMS  = SREAL * SCHUNKS;           // 840
constexpr int HPITCH = 48;                         // H_T row pitch (f16)
constexpr float C1c = 6.5025f;                     // (0.01*255)^2
constexpr float C2c = 58.5225f;                    // (0.03*255)^2

typedef _Float16 half8   __attribute__((ext_vector_type(8)));
typedef _Float16 half4   __attribute__((ext_vector_type(4)));
typedef float    floatv4 __attribute__((ext_vector_type(4)));

__device__ const float WF[11] = {
    0.00102838f, 0.00759876f, 0.03600077f, 0.10936069f, 0.21300553f,
    0.26601172f,
    0.21300553f, 0.10936069f, 0.03600077f, 0.00759876f, 0.00102838f
};

__global__ __launch_bounds__(256, 4)
void ssim_kernel(const float* __restrict__ X, const float* __restrict__ Y,
                 float* __restrict__ out)
{
    __shared__ __align__(16) _Float16 s_x[SROWS][SPITCH];   // 8448 B
    __shared__ __align__(16) _Float16 s_y[SROWS][SPITCH];   // 8448 B
    __shared__ __align__(16) _Float16 s_ht[2][TW][HPITCH];  // 12288 B
    __shared__ _Float16 s_wtab[16];

    const int tid  = threadIdx.x;
    const int lane = tid & 63;
    const int wv   = tid >> 6;          // wave id = outcol chunk
    const int col0 = blockIdx.x * TW;
    const int row0 = blockIdx.y * TH;
    const int n    = blockIdx.z;

    if (tid < 16) s_wtab[tid] = (tid < 11) ? (_Float16)WF[tid] : (_Float16)0.f;
    // zero-fill pad rows 42..47 once (never overwritten: stage loop r<42)
    {
        const _Float16 z0 = (_Float16)0.f;
        const half4 z4 = {z0, z0, z0, z0};
        for (int i = tid; i < (SROWS - SREAL) * SCHUNKS; i += 256) {
            int r = SREAL + i / SCHUNKS, c4 = (i % SCHUNKS) * 4;
            *(half4*)&s_x[r][c4] = z4;
            *(half4*)&s_y[r][c4] = z4;
        }
    }
    __syncthreads();

    // banded weight fragment B[k][n] = W[k-n]; lane: n=lane&15, k=(lane>>4)*8+j
    half8 bfrag;
    {
        const int bn = lane & 15, kq = (lane >> 4) * 8;
        #pragma unroll
        for (int j = 0; j < 8; ++j) {
            int kk = kq + j - bn;
            kk = (kk < 0 || kk > 10) ? 11 : kk;   // index 11 holds 0
            bfrag[j] = s_wtab[kk];
        }
    }

    float acc[2][4] = {{0.f,0.f,0.f,0.f},{0.f,0.f,0.f,0.f}};

    const size_t plane = (size_t)HH * WW;
    const float* Xn = X + (size_t)n * CC * plane;
    const float* Yn = Y + (size_t)n * CC * plane;

    const floatv4 zf = {0.f, 0.f, 0.f, 0.f};
    const int arow = lane & 15;              // A-operand m row sel
    const int aq   = lane >> 4;              // A-operand k quad
    const int crow = (lane >> 4) * 4;        // C-layout row base

    // ---- prefetch register file: this thread's staging chunks ----
    float4 px[4], py[4];

    auto prefetch = [&](int ch) {
        const float* Xc = Xn + (size_t)ch * plane;
        const float* Yc = Yn + (size_t)ch * plane;
        #pragma unroll
        for (int r4 = 0; r4 < 4; ++r4) {
            const int i = tid + r4 * 256;
            if (i < SITEMS) {
                int r = i / SCHUNKS, c4 = (i % SCHUNKS) * 4;
                int gr = row0 + r; gr = gr < HH ? gr : HH - 1;
                const float* bx = Xc + (size_t)gr * WW;
                const float* by = Yc + (size_t)gr * WW;
                if (col0 + c4 + 3 < WW) {          // uniform per thread
                    px[r4] = *(const float4*)(bx + col0 + c4);
                    py[r4] = *(const float4*)(by + col0 + c4);
                } else {                            // edge chunks only
                    float ax[4], ay[4];
                    #pragma unroll
                    for (int e = 0; e < 4; ++e) {
                        int gw = col0 + c4 + e; gw = gw < WW ? gw : WW - 1;
                        ax[e] = bx[gw]; ay[e] = by[gw];
                    }
                    px[r4] = make_float4(ax[0], ax[1], ax[2], ax[3]);
                    py[r4] = make_float4(ay[0], ay[1], ay[2], ay[3]);
                }
            }
        }
    };

    auto write_lds = [&]() {
        #pragma unroll
        for (int r4 = 0; r4 < 4; ++r4) {
            const int i = tid + r4 * 256;
            if (i < SITEMS) {
                int r = i / SCHUNKS, c4 = (i % SCHUNKS) * 4;
                half4 hx = {(_Float16)px[r4].x, (_Float16)px[r4].y,
                            (_Float16)px[r4].z, (_Float16)px[r4].w};
                half4 hy = {(_Float16)py[r4].x, (_Float16)py[r4].y,
                            (_Float16)py[r4].z, (_Float16)py[r4].w};
                *(half4*)&s_x[r][c4] = hx;
                *(half4*)&s_y[r][c4] = hy;
            }
        }
    };

    prefetch(0);

    for (int ch = 0; ch < CC; ++ch) {
        write_lds();
        __syncthreads();   // A: staging visible to all waves

        // ---- shared x/y A-fragments (reused by all 5 quantities) ----
        half8 axf[3], ayf[3];
        #pragma unroll
        for (int rc = 0; rc < 3; ++rc) {
            axf[rc] = *(const half8*)&s_x[rc*16 + arow][wv*16 + aq*8];
            ayf[rc] = *(const half8*)&s_y[rc*16 + arow][wv*16 + aq*8];
        }
        __syncthreads();   // B: all s_x/s_y reads done (lgkm drain only)

        // issue next channel's global loads now: they stay in flight across
        // the whole MFMA section (no barrier until next write_lds)
        if (ch + 1 < CC) prefetch(ch + 1);

        // ---- H + V MFMA per quantity (ping-pong s_ht, wave-private) ----
        floatv4 vfr[5][2];
        #pragma unroll
        for (int q = 0; q < 5; ++q) {
            _Float16* hb = &s_ht[q & 1][0][0];
            #pragma unroll
            for (int rc = 0; rc < 3; ++rc) {
                half8 a;
                if      (q == 0) a = axf[rc];
                else if (q == 1) a = ayf[rc];
                else if (q == 2) a = axf[rc] * axf[rc];
                else if (q == 3) a = ayf[rc] * ayf[rc];
                else             a = axf[rc] * ayf[rc];
                floatv4 d = __builtin_amdgcn_mfma_f32_16x16x32_f16(
                    a, bfrag, zf, 0, 0, 0);
                half4 h = {(_Float16)d[0], (_Float16)d[1],
                           (_Float16)d[2], (_Float16)d[3]};
                *(half4*)&hb[(wv*16 + arow) * HPITCH + rc*16 + crow] = h;
            }
            #pragma unroll
            for (int b = 0; b < 2; ++b) {
                half8 av = *(const half8*)
                    &hb[(wv*16 + arow) * HPITCH + b*16 + aq*8];
                vfr[q][b] = __builtin_amdgcn_mfma_f32_16x16x32_f16(
                    av, bfrag, zf, 0, 0, 0);
            }
        }

        // ---- SSIM on V fragments ----
        #pragma unroll
        for (int b = 0; b < 2; ++b) {
            #pragma unroll
            for (int p = 0; p < 4; ++p) {
                float m1 = vfr[0][b][p], m2 = vfr[1][b][p];
                float exx = vfr[2][b][p], eyy = vfr[3][b][p],
                      exy = vfr[4][b][p];
                float m1s = m1*m1, m2s = m2*m2, m12 = m1*m2;
                float s1 = exx - m1s, s2 = eyy - m2s, s12 = exy - m12;
                float n1 = 2.f*m12 + C1c, d1 = m1s + m2s + C1c;
                float n2 = 2.f*s12 + C2c, d2 = s1 + s2 + C2c;
                acc[b][p] = fmaf(n1 * n2, __builtin_amdgcn_rcpf(d1 * d2),
                                 acc[b][p]);
            }
        }
    }

    // ---- epilogue: 1 - mean over channels ----
    #pragma unroll
    for (int b = 0; b < 2; ++b) {
        const int orow = row0 + b*16 + arow;
        const int ocol = col0 + wv*16 + crow;
        if (orow < OH) {
            float r0v = 1.f - acc[b][0] * (1.f/3.f);
            float r1v = 1.f - acc[b][1] * (1.f/3.f);
            float r2v = 1.f - acc[b][2] * (1.f/3.f);
            float r3v = 1.f - acc[b][3] * (1.f/3.f);
            size_t base = ((size_t)n * OH + orow) * OW + ocol;
            if (ocol + 3 < OW) {
                *(float2*)(out + base)     = make_float2(r0v, r1v);
                *(float2*)(out + base + 2) = make_float2(r2v, r3v);
            } else {
                float rs[4] = {r0v, r1v, r2v, r3v};
                #pragma unroll
                for (int p = 0; p < 4; ++p)
                    if (ocol + p < OW) out[base + p] = rs[p];
            }
        }
    }
}

} // namespace

extern "C" void kernel_launch(void* const* d_in, const int* in_sizes, int n_in,
                              void* d_out, int out_size, void* d_ws, size_t ws_size,
                              hipStream_t stream) {
    const float* X = (const float*)d_in[0];
    const float* Y = (const float*)d_in[1];
    float* out = (float*)d_out;

    dim3 grid((OW + TW - 1) / TW,   // 8
              (OH + TH - 1) / TH,   // 16
              NN);                  // 16
    ssim_kernel<<<grid, 256, 0, stream>>>(X, Y, out);
}

// Round 6
// 140.427 us; speedup vs baseline: 1.3474x; 1.3474x over previous
//
#include <hip/hip_runtime.h>

// SSIM (win=11, sigma=1.5, range=255), N=16 C=3 512x512 fp32 -> [16,502,502].
// R6: barrier-free waves. R5's register prefetch spilled (WRITE_SIZE 17->127MB
// = scratch traffic); R3-R5's real flaw was the block-wide serial
// stage->barrier->compute chain. Fix: drop x/y LDS staging entirely -- each
// wave loads its A-fragment regions (16x32 f32 per rc) straight from global
// (12 independent global_load_dwordx4 per wave-channel; 1.6x col halo
// re-read, absorbed by L2/L3 -- HBM was at 19% of peak). No __syncthreads in
// the channel loop at all: waves self-schedule, latency hides across 5
// waves/SIMD. LDS = s_ht only (6.3 kB, single buffer -- per-wave DS ordering
// makes write(q+1)-after-read(q) safe, validated R3-R5).
//
// Edge clamps (uniform min(), no scalar fallback): clamped cols/rows feed
// only zero band-weights (staged row r feeds outrow n iff 0<=r-n<=10; rows
// 42..47 / clamped rows at y=15 give r-n>10 for all valid n) or outputs
// masked at the store (outcol>501 / outrow>501).
//
// MFMA scheme (mfma_f32_16x16x32_f16), B[k][n] = W[k-n] banded, both passes:
//  H: A[m=row][k=col] -> D[m=row][n=outcol]; C-layout (col=lane&15,
//     row=(lane>>4)*4+reg) -> ds_write_b64 transposed into H_T[outcol][row].
//  V: A[m=outcol][k=row] from H_T (k contiguous -> ds_read_b128),
//     D[m=outcol][n=outrow]. Wave owns outcol chunk for both passes.
//  x^2/y^2/xy A-frags derived in registers (v_pk_mul_f16 of x/y frags).
// HPITCH=48 f16 (96 B): H-write b64 and V-read b128 patterns both spread
// uniformly over 32 banks (4 row-groups x dense 8/16-bank spans).

namespace {

constexpr int NN = 16, CC = 3, HH = 512, WW = 512;
constexpr int OH = HH - 10, OW = WW - 10;          // 502 x 502
constexpr int TW = 64, TH = 32;                    // output tile per block
constexpr int HPITCH = 48;                         // H_T row pitch (f16)
constexpr float C1c = 6.5025f;                     // (0.01*255)^2
constexpr float C2c = 58.5225f;                    // (0.03*255)^2

typedef _Float16 half8   __attribute__((ext_vector_type(8)));
typedef _Float16 half4   __attribute__((ext_vector_type(4)));
typedef float    floatv4 __attribute__((ext_vector_type(4)));

__device__ const float WF[11] = {
    0.00102838f, 0.00759876f, 0.03600077f, 0.10936069f, 0.21300553f,
    0.26601172f,
    0.21300553f, 0.10936069f, 0.03600077f, 0.00759876f, 0.00102838f
};

__device__ inline half8 pack8(const float4& a, const float4& b) {
    half8 h = {(_Float16)a.x, (_Float16)a.y, (_Float16)a.z, (_Float16)a.w,
               (_Float16)b.x, (_Float16)b.y, (_Float16)b.z, (_Float16)b.w};
    return h;
}

__global__ __launch_bounds__(256, 2)
void ssim_kernel(const float* __restrict__ X, const float* __restrict__ Y,
                 float* __restrict__ out)
{
    __shared__ __align__(16) _Float16 s_ht[TW][HPITCH];   // 6144 B
    __shared__ _Float16 s_wtab[16];

    const int tid  = threadIdx.x;
    const int lane = tid & 63;
    const int wv   = tid >> 6;          // wave id = outcol chunk (16 cols)
    const int col0 = blockIdx.x * TW;
    const int row0 = blockIdx.y * TH;
    const int n    = blockIdx.z;

    if (tid < 16) s_wtab[tid] = (tid < 11) ? (_Float16)WF[tid] : (_Float16)0.f;
    __syncthreads();   // only block-wide sync in the kernel

    // banded weight fragment B[k][n] = W[k-n]; lane: n=lane&15, k=(lane>>4)*8+j
    half8 bfrag;
    {
        const int bn = lane & 15, kq = (lane >> 4) * 8;
        #pragma unroll
        for (int j = 0; j < 8; ++j) {
            int kk = kq + j - bn;
            kk = (kk < 0 || kk > 10) ? 11 : kk;   // index 11 holds 0
            bfrag[j] = s_wtab[kk];
        }
    }

    const int arow = lane & 15;          // A m-row select / V outrow-local
    const int aq   = lane >> 4;          // A k-quad
    const int crow = aq * 4;             // C-layout row base

    // global addresses for this lane's A-fragment loads (uniform clamps;
    // clamped lanes feed only zero-weight taps or masked-off outputs)
    int gcol = col0 + wv * 16 + aq * 8;
    gcol = gcol <= WW - 8 ? gcol : WW - 8;         // stays 32B-aligned
    int grow[3];
    #pragma unroll
    for (int rc = 0; rc < 3; ++rc) {
        int g = row0 + rc * 16 + arow;
        grow[rc] = g < HH ? g : HH - 1;
    }

    float acc[2][4] = {{0.f,0.f,0.f,0.f},{0.f,0.f,0.f,0.f}};

    const size_t plane = (size_t)HH * WW;
    const float* Xn = X + (size_t)n * CC * plane;
    const float* Yn = Y + (size_t)n * CC * plane;
    const floatv4 zf = {0.f, 0.f, 0.f, 0.f};

    for (int ch = 0; ch < CC; ++ch) {
        const float* Xc = Xn + (size_t)ch * plane;
        const float* Yc = Yn + (size_t)ch * plane;

        // ---- 12 independent dwordx4 loads: this wave's 3 rc x 32-col
        // A-regions for x and y ----
        float4 fx[3][2], fy[3][2];
        #pragma unroll
        for (int rc = 0; rc < 3; ++rc) {
            const float* bx = Xc + (size_t)grow[rc] * WW + gcol;
            const float* by = Yc + (size_t)grow[rc] * WW + gcol;
            fx[rc][0] = *(const float4*)bx;
            fx[rc][1] = *(const float4*)(bx + 4);
            fy[rc][0] = *(const float4*)by;
            fy[rc][1] = *(const float4*)(by + 4);
        }

        half8 axf[3], ayf[3];
        #pragma unroll
        for (int rc = 0; rc < 3; ++rc) {
            axf[rc] = pack8(fx[rc][0], fx[rc][1]);
            ayf[rc] = pack8(fy[rc][0], fy[rc][1]);
        }

        // ---- H + V MFMA per quantity (s_ht wave-private; per-wave DS
        // in-order => single buffer reuse across q is safe) ----
        floatv4 vfr[5][2];
        #pragma unroll
        for (int q = 0; q < 5; ++q) {
            #pragma unroll
            for (int rc = 0; rc < 3; ++rc) {
                half8 a;
                if      (q == 0) a = axf[rc];
                else if (q == 1) a = ayf[rc];
                else if (q == 2) a = axf[rc] * axf[rc];
                else if (q == 3) a = ayf[rc] * ayf[rc];
                else             a = axf[rc] * ayf[rc];
                floatv4 d = __builtin_amdgcn_mfma_f32_16x16x32_f16(
                    a, bfrag, zf, 0, 0, 0);
                half4 h = {(_Float16)d[0], (_Float16)d[1],
                           (_Float16)d[2], (_Float16)d[3]};
                *(half4*)&s_ht[wv*16 + arow][rc*16 + crow] = h;
            }
            #pragma unroll
            for (int b = 0; b < 2; ++b) {
                half8 av = *(const half8*)&s_ht[wv*16 + arow][b*16 + aq*8];
                vfr[q][b] = __builtin_amdgcn_mfma_f32_16x16x32_f16(
                    av, bfrag, zf, 0, 0, 0);
            }
        }

        // ---- SSIM on V fragments ----
        #pragma unroll
        for (int b = 0; b < 2; ++b) {
            #pragma unroll
            for (int p = 0; p < 4; ++p) {
                float m1 = vfr[0][b][p], m2 = vfr[1][b][p];
                float exx = vfr[2][b][p], eyy = vfr[3][b][p],
                      exy = vfr[4][b][p];
                float m1s = m1*m1, m2s = m2*m2, m12 = m1*m2;
                float s1 = exx - m1s, s2 = eyy - m2s, s12 = exy - m12;
                float n1 = 2.f*m12 + C1c, d1 = m1s + m2s + C1c;
                float n2 = 2.f*s12 + C2c, d2 = s1 + s2 + C2c;
                acc[b][p] = fmaf(n1 * n2, __builtin_amdgcn_rcpf(d1 * d2),
                                 acc[b][p]);
            }
        }
    }

    // ---- epilogue: 1 - mean over channels ----
    #pragma unroll
    for (int b = 0; b < 2; ++b) {
        const int orow = row0 + b*16 + arow;
        const int ocol = col0 + wv*16 + crow;
        if (orow < OH) {
            float r0v = 1.f - acc[b][0] * (1.f/3.f);
            float r1v = 1.f - acc[b][1] * (1.f/3.f);
            float r2v = 1.f - acc[b][2] * (1.f/3.f);
            float r3v = 1.f - acc[b][3] * (1.f/3.f);
            size_t base = ((size_t)n * OH + orow) * OW + ocol;
            if (ocol + 3 < OW) {
                *(float2*)(out + base)     = make_float2(r0v, r1v);
                *(float2*)(out + base + 2) = make_float2(r2v, r3v);
            } else {
                float rs[4] = {r0v, r1v, r2v, r3v};
                #pragma unroll
                for (int p = 0; p < 4; ++p)
                    if (ocol + p < OW) out[base + p] = rs[p];
            }
        }
    }
}

} // namespace

extern "C" void kernel_launch(void* const* d_in, const int* in_sizes, int n_in,
                              void* d_out, int out_size, void* d_ws, size_t ws_size,
                              hipStream_t stream) {
    const float* X = (const float*)d_in[0];
    const float* Y = (const float*)d_in[1];
    float* out = (float*)d_out;

    dim3 grid((OW + TW - 1) / TW,   // 8
              (OH + TH - 1) / TH,   // 16
              NN);                  // 16
    ssim_kernel<<<grid, 256, 0, stream>>>(X, Y, out);
}